// Round 4
// baseline (213.649 us; speedup 1.0000x reference)
//
#include <hip/hip_runtime.h>

#define VOCAB 8192
#define CTX 4
#define BATCH 1024
#define OBLK 32                  // fc_w rows (output columns) per workgroup
#define NCHUNK (OBLK * CTX)      // 128 chunks of VOCAB floats each
#define RING 4                   // LDS ring depth (4 x 32 KB = 128 KB)

// One WG per CU (grid=256): 1024 threads (thread t == batch b), 32 consecutive
// output columns. Streams a contiguous 4 MB slice of fc_w through a 4-deep
// LDS ring with a 2-chunk register stage:
//   iter k: issue loads chunk k+4 -> regs; ds_write chunk k+2 (regs from iter
//   k-2, counted vmcnt(4) -- 2-chunk issue->write slack); gather chunk k;
//   raw barrier draining lgkmcnt only (vmcnt stays counted across it).
// Load->use slack = 4 chunks (~10 us): outstanding reads 64 KB/CU sustained,
// convoy jitter absorbed by the ring.
__global__ __launch_bounds__(1024) void cbow_kernel(
    const int*   __restrict__ contexts,   // [1024, 4] int32
    const float* __restrict__ fc_w,       // [8192, 32768] row-major f32
    const float* __restrict__ fc_b,       // [8192] f32
    float*       __restrict__ out)        // [1024, 8192] f32
{
    __shared__ float lds[RING][VOCAB];    // 128 KB -> 1 WG/CU (m201 precedent)

    const int t  = threadIdx.x;           // == batch index b
    const int o0 = blockIdx.x * OBLK;
    const size_t base = (size_t)o0 * (CTX * VOCAB);  // this WG's contiguous slice

    const int4 cv = ((const int4*)contexts)[t];
    const int cc[4] = {cv.x, cv.y, cv.z, cv.w};

    float acc[OBLK];
#pragma unroll
    for (int j = 0; j < OBLK; ++j) acc[j] = fc_b[o0 + j];

    // Prologue: chunks 0,1 -> LDS ring[0,1]; chunks 2,3 held in registers.
#pragma unroll
    for (int k = 0; k < 2; ++k) {
        const float4* src = (const float4*)(fc_w + base + (size_t)k * VOCAB);
        float4 a = src[t];
        float4 b = src[1024 + t];
        float4* dst = (float4*)lds[k];
        dst[t]        = a;
        dst[1024 + t] = b;
    }
    const float4* s2 = (const float4*)(fc_w + base + (size_t)2 * VOCAB);
    float4 pa = s2[t];
    float4 pb = s2[1024 + t];
    const float4* s3 = (const float4*)(fc_w + base + (size_t)3 * VOCAB);
    float4 na = s3[t];
    float4 nb = s3[1024 + t];
    asm volatile("s_waitcnt lgkmcnt(0)\n\ts_barrier" ::: "memory");

    // Main loop, fully unrolled: all acc/cc indices and ring slots compile-time.
#pragma unroll
    for (int k = 0; k < NCHUNK; ++k) {
        float4 fa, fb;                    // loads for chunk k+4 (issue FIRST)
        if (k + 4 < NCHUNK) {
            const float4* src = (const float4*)(fc_w + base + (size_t)(k + 4) * VOCAB);
            fa = src[t];
            fb = src[1024 + t];
        }

        if (k + 2 < NCHUNK) {             // write chunk k+2 from regs loaded at
            float4* dst = (float4*)lds[(k + 2) & (RING - 1)];  // iter k-2 -> vmcnt(4)
            dst[t]        = pa;
            dst[1024 + t] = pb;
        }

        // Gather chunk k (row k>>2, ctx position k&3); ring slot written at
        // iter k-2, cross-wave visible since barrier k-1.
        acc[k >> 2] += lds[k & (RING - 1)][cc[k & 3]];

        pa = na; pb = nb;                 // rotate register stage
        na = fa; nb = fb;

        // LDS-only cross-wave hazards: drain lgkmcnt, NOT vmcnt, then barrier.
        if (k < NCHUNK - 1)
            asm volatile("s_waitcnt lgkmcnt(0)\n\ts_barrier" ::: "memory");
    }

    // Epilogue: thread t writes out[t, o0..o0+31] = 128 contiguous bytes
    // (two full cache lines, fully written).
    float4* op = (float4*)(out + (size_t)t * VOCAB + o0);
#pragma unroll
    for (int j = 0; j < OBLK / 4; ++j) {
        float4 v;
        v.x = acc[4 * j + 0];
        v.y = acc[4 * j + 1];
        v.z = acc[4 * j + 2];
        v.w = acc[4 * j + 3];
        op[j] = v;
    }
}

extern "C" void kernel_launch(void* const* d_in, const int* in_sizes, int n_in,
                              void* d_out, int out_size, void* d_ws, size_t ws_size,
                              hipStream_t stream) {
    const int*   contexts = (const int*)d_in[0];
    const float* fc_w     = (const float*)d_in[1];
    const float* fc_b     = (const float*)d_in[2];
    float*       out      = (float*)d_out;

    dim3 grid(VOCAB / OBLK);   // 256 workgroups == 256 CUs, 1 per CU, no tail
    dim3 block(1024);
    cbow_kernel<<<grid, block, 0, stream>>>(contexts, fc_w, fc_b, out);
}